// Round 1
// 621.353 us; speedup vs baseline: 1.0629x; 1.0629x over previous
//
#include <hip/hip_runtime.h>
#include <cstdint>

// TriplaneEncoding, fp32 I/O. N=2^20 points, 4 levels (r=128,256,512,1024),
// C=4, 3 planes.  out[n, l*12 + p*4 + c] = plane_bilinear * line
// Line sample is degenerate (W=1 axis carries the coord, H axis fixed 0):
//   line = w(t) * 0.5*(TL[p,c,r/2-1] + TL[p,c,r/2]).
//
// R5 design: latency-bound gather (VALUBusy 3.8%, 36 VGPR, 58% HBM).
//  - main kernel split: thread = (point, level) so 12 float4 gathers issue
//    back-to-back per thread at high occupancy (MLP up ~2-3x).
//  - output buffered in regs, burst non-temporal stores (WRITE_SIZE was 2x out).
//  - aux fused to ONE kernel: texel-per-thread repack (coalesced read streams +
//    float4 write) + line consts in threads t<48.  6 launches -> 2.

typedef float f32x4 __attribute__((ext_vector_type(4)));

// Workspace layout in floats:
static constexpr int LVL_OFF[4] = {0, 196608, 983040, 4128768};
static constexpr int S_OFF = 16711680;   // 48 fp32 line constants after planes
static constexpr size_t WS_NEED = (size_t)(S_OFF + 48) * sizeof(float);
static constexpr int TEXELS = 4177920;   // 3*(128^2+256^2+512^2+1024^2)

// ---------------- fused repack + line consts ----------------
// (3, C, r, r) -> (3, r*r, C) float4 texels for all levels in one launch.
// Reads: 4 coalesced scalar streams (256B/wave each). Writes: coalesced float4.
__global__ __launch_bounds__(256) void repack_all(
        const float* __restrict__ tp0, const float* __restrict__ tp1,
        const float* __restrict__ tp2, const float* __restrict__ tp3,
        const float* __restrict__ tl0, const float* __restrict__ tl1,
        const float* __restrict__ tl2, const float* __restrict__ tl3,
        float* __restrict__ ws) {
    int t = blockIdx.x * 256 + threadIdx.x;     // global texel id, < TEXELS
    const float* src; int rr_shift, texoff;
    if (t < 49152)        { src = tp0; rr_shift = 14; texoff = 0; }
    else if (t < 245760)  { src = tp1; rr_shift = 16; texoff = 49152; }
    else if (t < 1032192) { src = tp2; rr_shift = 18; texoff = 245760; }
    else                  { src = tp3; rr_shift = 20; texoff = 1032192; }
    int local = t - texoff;                     // p*r*r + yx within level
    int p  = local >> rr_shift;
    int yx = local & ((1 << rr_shift) - 1);
    const float* s0 = src + ((size_t)(p << 2) << rr_shift) + yx;
    float4 o;
    o.x = s0[0];
    o.y = s0[(size_t)1 << rr_shift];
    o.z = s0[(size_t)2 << rr_shift];
    o.w = s0[(size_t)3 << rr_shift];
    reinterpret_cast<float4*>(ws)[t] = o;
    if (t < 48) {   // line constants: rows r/2-1, r/2 at weight 0.5 each
        int ll = t / 12, rem = t % 12, pp = rem >> 2, cc = rem & 3;
        const float* tl = (ll == 0) ? tl0 : (ll == 1) ? tl1 : (ll == 2) ? tl2 : tl3;
        int r = 128 << ll;
        const float* row = tl + (size_t)((pp << 2) + cc) * r;
        int y0 = (r >> 1) - 1;
        ws[S_OFF + t] = 0.5f * row[y0] + 0.5f * row[y0 + 1];
    }
}

// ---------------- bilinear helpers ----------------
struct BilinW {
    int i00, i10, i01, i11;     // clamped linear indices (y*r + x)
    float w00, w10, w01, w11;   // weights * validity (zero padding)
};

__device__ __forceinline__ BilinW bilin_weights(int r, float u, float v) {
    float fr = (float)r;
    float fx = (u + 1.0f) * 0.5f * fr - 0.5f;
    float fy = (v + 1.0f) * 0.5f * fr - 0.5f;
    float x0f = floorf(fx), y0f = floorf(fy);
    float wx = fx - x0f, wy = fy - y0f;
    int x0 = (int)x0f, y0 = (int)y0f;
    int x1 = x0 + 1, y1 = y0 + 1;
    float vx0 = ((unsigned)x0 < (unsigned)r) ? 1.0f : 0.0f;
    float vx1 = ((unsigned)x1 < (unsigned)r) ? 1.0f : 0.0f;
    float vy0 = ((unsigned)y0 < (unsigned)r) ? 1.0f : 0.0f;
    float vy1 = ((unsigned)y1 < (unsigned)r) ? 1.0f : 0.0f;
    int x0c = min(max(x0, 0), r - 1), x1c = min(max(x1, 0), r - 1);
    int y0c = min(max(y0, 0), r - 1), y1c = min(max(y1, 0), r - 1);
    BilinW b;
    b.i00 = y0c * r + x0c; b.i10 = y0c * r + x1c;
    b.i01 = y1c * r + x0c; b.i11 = y1c * r + x1c;
    b.w00 = (1.0f - wx) * (1.0f - wy) * vx0 * vy0;
    b.w10 = wx * (1.0f - wy) * vx1 * vy0;
    b.w01 = (1.0f - wx) * wy * vx0 * vy1;
    b.w11 = wx * wy * vx1 * vy1;
    return b;
}

__device__ __forceinline__ float line_w(float t) {
    float fx = (t + 1.0f) * 0.5f - 0.5f;     // W = 1 axis
    float x0f = floorf(fx);
    float wx = fx - x0f;
    int x0 = (int)x0f;
    float w = 0.0f;
    if (x0 == 0) w += 1.0f - wx;     // col 0 valid as "left" corner
    if (x0 == -1) w += wx;           // col 0 valid as "right" corner
    return w;
}

__device__ __forceinline__ f32x4 bacc(const float4& A, const float4& B2,
                                      const float4& C2, const float4& D,
                                      const BilinW& b, const float4& s, float lw) {
    f32x4 o;
    o.x = (A.x * b.w00 + B2.x * b.w10 + C2.x * b.w01 + D.x * b.w11) * (s.x * lw);
    o.y = (A.y * b.w00 + B2.y * b.w10 + C2.y * b.w01 + D.y * b.w11) * (s.y * lw);
    o.z = (A.z * b.w00 + B2.z * b.w10 + C2.z * b.w01 + D.z * b.w11) * (s.z * lw);
    o.w = (A.w * b.w00 + B2.w * b.w10 + C2.w * b.w01 + D.w * b.w11) * (s.w * lw);
    return o;
}

// ---------------- main kernel: thread = (point, level) ----------------
template <bool VEC4OUT>
__global__ __launch_bounds__(256, 2) void tri_split4(
        const float* __restrict__ x, const float4* __restrict__ planes,
        const float* __restrict__ S, float* __restrict__ out, int N) {
    int gid = blockIdx.x * 256 + threadIdx.x;
    int n = gid >> 2;
    int l = gid & 3;            // l fastest -> wave writes a dense 3KB span
    if (n >= N) return;
    float ax = x[n * 3 + 0] * 2.0f - 1.0f;
    float ay = x[n * 3 + 1] * 2.0f - 1.0f;
    float az = x[n * 3 + 2] * 2.0f - 1.0f;
    const int r = 128 << l;
    const int rr = r * r;
    int texoff = (l == 0) ? 0 : (l == 1) ? 49152 : (l == 2) ? 245760 : 1032192;
    const float4* G0 = planes + texoff;
    const float4* G1 = G0 + rr;
    const float4* G2 = G1 + rr;
    // plane p (u = W axis, v = H axis): p0:(x,z) p1:(y,x) p2:(z,y)
    BilinW b0 = bilin_weights(r, ax, az);
    BilinW b1 = bilin_weights(r, ay, ax);
    BilinW b2 = bilin_weights(r, az, ay);
    // issue all 12 gathers before any consumption (MLP)
    float4 g0a = G0[b0.i00], g0b = G0[b0.i10], g0c = G0[b0.i01], g0d = G0[b0.i11];
    float4 g1a = G1[b1.i00], g1b = G1[b1.i10], g1c = G1[b1.i01], g1d = G1[b1.i11];
    float4 g2a = G2[b2.i00], g2b = G2[b2.i10], g2c = G2[b2.i01], g2d = G2[b2.i11];
    float lw0 = line_w(ax), lw1 = line_w(ay), lw2 = line_w(az);
    const float4* S4 = reinterpret_cast<const float4*>(S);
    float4 s0 = S4[l * 3 + 0], s1 = S4[l * 3 + 1], s2 = S4[l * 3 + 2];

    f32x4 o0 = bacc(g0a, g0b, g0c, g0d, b0, s0, lw0);
    f32x4 o1 = bacc(g1a, g1b, g1c, g1d, b1, s1, lw1);
    f32x4 o2 = bacc(g2a, g2b, g2c, g2d, b2, s2, lw2);

    size_t base = (size_t)n * 48 + (size_t)l * 12;
    if (VEC4OUT) {
        f32x4* op = reinterpret_cast<f32x4*>(out + base);
        __builtin_nontemporal_store(o0, op);        // write-once stream:
        __builtin_nontemporal_store(o1, op + 1);    // keep out of L2
        __builtin_nontemporal_store(o2, op + 2);
    } else {
        out[base + 0] = o0.x; out[base + 1]  = o0.y;
        out[base + 2] = o0.z; out[base + 3]  = o0.w;
        out[base + 4] = o1.x; out[base + 5]  = o1.y;
        out[base + 6] = o1.z; out[base + 7]  = o1.w;
        out[base + 8] = o2.x; out[base + 9]  = o2.y;
        out[base + 10] = o2.z; out[base + 11] = o2.w;
    }
}

// ---------------- fallback: direct layout, scalar I/O ----------------
__global__ __launch_bounds__(256) void tri_direct(
        const float* __restrict__ x,
        const float* __restrict__ tp0, const float* __restrict__ tp1,
        const float* __restrict__ tp2, const float* __restrict__ tp3,
        const float* __restrict__ tl0, const float* __restrict__ tl1,
        const float* __restrict__ tl2, const float* __restrict__ tl3,
        float* __restrict__ out, int N) {
    int n = blockIdx.x * blockDim.x + threadIdx.x;
    if (n >= N) return;
    float ax = x[n * 3 + 0] * 2.0f - 1.0f;
    float ay = x[n * 3 + 1] * 2.0f - 1.0f;
    float az = x[n * 3 + 2] * 2.0f - 1.0f;
    const float U[3] = {ax, ay, az};
    const float V[3] = {az, ax, ay};
    const float LW[3] = {line_w(ax), line_w(ay), line_w(az)};
    const float* TP[4] = {tp0, tp1, tp2, tp3};
    const float* TL[4] = {tl0, tl1, tl2, tl3};

#pragma unroll
    for (int l = 0; l < 4; ++l) {
        const int r = 128 << l;
        const int rr = r * r;
        const int y0 = (r >> 1) - 1;
#pragma unroll
        for (int p = 0; p < 3; ++p) {
            const float* G = TP[l] + (size_t)(p * 4) * rr;
            BilinW b = bilin_weights(r, U[p], V[p]);
            const float w = LW[p];
#pragma unroll
            for (int c = 0; c < 4; ++c) {
                const float* Gc = G + (size_t)c * rr;
                float acc = Gc[b.i00] * b.w00 + Gc[b.i10] * b.w10 +
                            Gc[b.i01] * b.w01 + Gc[b.i11] * b.w11;
                const float* row = TL[l] + (size_t)((p << 2) + c) * r;
                float s = 0.5f * row[y0] + 0.5f * row[y0 + 1];
                out[(size_t)n * 48 + l * 12 + p * 4 + c] = acc * (s * w);
            }
        }
    }
}

extern "C" void kernel_launch(void* const* d_in, const int* in_sizes, int n_in,
                              void* d_out, int out_size, void* d_ws, size_t ws_size,
                              hipStream_t stream) {
    const float* x = (const float*)d_in[0];
    const float* tp[4];
    const float* tl[4];
    // setup_inputs() dict order is interleaved: x, tp0, tl0, tp1, tl1, ...
    // (triline_0 has 3*4*128 = 1536 elements; triplane_0 has 196608).
    bool interleaved = (n_in >= 9) && (in_sizes[2] == 1536);
    for (int l = 0; l < 4; ++l) {
        if (interleaved) {
            tp[l] = (const float*)d_in[1 + 2 * l];
            tl[l] = (const float*)d_in[2 + 2 * l];
        } else {
            tp[l] = (const float*)d_in[1 + l];
            tl[l] = (const float*)d_in[5 + l];
        }
    }
    int N = in_sizes[0] / 3;
    float* out = (float*)d_out;

    bool ws_ok = (ws_size >= WS_NEED) && (((uintptr_t)d_ws & 15u) == 0);
    if (ws_ok) {
        float* ws = (float*)d_ws;
        repack_all<<<TEXELS / 256, 256, 0, stream>>>(
            tp[0], tp[1], tp[2], tp[3], tl[0], tl[1], tl[2], tl[3], ws);
        long long total = 4LL * N;
        int grid = (int)((total + 255) / 256);
        if (((uintptr_t)d_out & 15u) == 0) {
            tri_split4<true><<<grid, 256, 0, stream>>>(
                x, (const float4*)ws, ws + S_OFF, out, N);
        } else {
            tri_split4<false><<<grid, 256, 0, stream>>>(
                x, (const float4*)ws, ws + S_OFF, out, N);
        }
    } else {
        int grid = (N + 255) / 256;
        tri_direct<<<grid, 256, 0, stream>>>(
            x, tp[0], tp[1], tp[2], tp[3], tl[0], tl[1], tl[2], tl[3], out, N);
    }
}

// Round 2
// 558.348 us; speedup vs baseline: 1.1828x; 1.1128x over previous
//
#include <hip/hip_runtime.h>
#include <cstdint>

// TriplaneEncoding, fp32 I/O. N=2^20 points, 4 levels (r=128,256,512,1024),
// C=4, 3 planes.  out[n, l*12 + p*4 + c] = plane_bilinear * line
// Line sample is degenerate: line = w(t) * 0.5*(TL[p,c,r/2-1] + TL[p,c,r/2]).
//
// R6 design: R0/R1 both pinned at ~1.5 GB TCC traffic / ~4 TB/s (VALUBusy 6%,
// occ 86%) -> either fabric-BW-bound or request-rate-bound. Cut LINE REQUESTS:
//  - levels 0-2 repacked as 2x2 pre-gathered 64B-aligned quads on an (r+1)^2
//    grid with OOB texels baked to zero: 1 sample = 1 line req (was ~2.25),
//    and clamp/validity VALU disappears (weights are pure bilinear).
//  - level 3 stays channel-last float4 (replicating it = 202 MB, blows L3).
//  - 12 threads/point (k = l*3+p fastest): store is out4[gid] -> every wave
//    store instr = dense 1KB NT burst (removes partial-sector write waste).
//  Requests/pt: 27 -> ~15.75. ws tiers: 117MB quad path > 67MB R1 path > direct.

typedef float f32x4 __attribute__((ext_vector_type(4)));

// ---------------- tier-1 workspace layout (float4 units unless noted) ----------------
// [ quads L0 | quads L1 | quads L2 | L3 texels | S(48 floats) ]
static constexpr int QE0 = 199692;              // 4*3*129^2
static constexpr int QE1 = 992280;              // QE0 + 4*3*257^2
static constexpr int QE2 = 4150308;             // QE1 + 4*3*513^2  (= L3 base, f4)
static constexpr int L3T = 3145728;             // 3*1024^2 texels
static constexpr int TOTAL_SLOTS = QE2 + L3T;   // 7296036 prep threads
static constexpr int S_OFFF = (QE2 + L3T) * 4;  // 29184144 floats
static constexpr size_t WS1_NEED = (size_t)(S_OFFF + 48) * sizeof(float);

// ---------------- tier-2 (R1) workspace layout ----------------
static constexpr int LVL_OFF[4] = {0, 196608, 983040, 4128768};
static constexpr int S_OFF2 = 16711680;
static constexpr size_t WS2_NEED = (size_t)(S_OFF2 + 48) * sizeof(float);
static constexpr int TEXELS = 4177920;          // 3*(128^2+256^2+512^2+1024^2)

// ==================== tier-1 prep: quads L0-2, texels L3, S ====================
__global__ __launch_bounds__(256) void prep_all(
        const float* __restrict__ tp0, const float* __restrict__ tp1,
        const float* __restrict__ tp2, const float* __restrict__ tp3,
        const float* __restrict__ tl0, const float* __restrict__ tl1,
        const float* __restrict__ tl2, const float* __restrict__ tl3,
        float* __restrict__ ws) {
    int t = blockIdx.x * 256 + threadIdx.x;
    if (t < 48) {   // line constants: rows r/2-1, r/2 at weight 0.5 each
        int ll = t / 12, rem = t % 12, pp = rem >> 2, cc = rem & 3;
        const float* tl = (ll == 0) ? tl0 : (ll == 1) ? tl1 : (ll == 2) ? tl2 : tl3;
        int r = 128 << ll;
        const float* row = tl + (size_t)((pp << 2) + cc) * r;
        int y0 = (r >> 1) - 1;
        ws[S_OFFF + t] = 0.5f * row[y0] + 0.5f * row[y0 + 1];
    }
    if (t >= TOTAL_SLOTS) return;
    float4* ws4 = reinterpret_cast<float4*>(ws);
    if (t < QE2) {
        // one 2x2-quad corner slot: slot s of quad q, level lvl
        const float* src; int lvl, base;
        if (t < QE0)      { src = tp0; lvl = 0; base = 0; }
        else if (t < QE1) { src = tp1; lvl = 1; base = QE0; }
        else              { src = tp2; lvl = 2; base = QE1; }
        int lt = t - base;
        int q = lt >> 2, s = lt & 3;
        int r = 128 << lvl, R = r + 1, rr_shift = 2 * (7 + lvl);
        int RR = R * R;
        int p   = q / RR;
        int rem = q - p * RR;
        int yq  = rem / R;
        int xq  = rem - yq * R;
        int tx = xq - 1 + (s & 1);
        int ty = yq - 1 + (s >> 1);
        float4 o = {0.f, 0.f, 0.f, 0.f};
        if ((unsigned)tx < (unsigned)r && (unsigned)ty < (unsigned)r) {
            const float* sp = src + ((size_t)(p << 2) << rr_shift) + (size_t)ty * r + tx;
            o.x = sp[0];
            o.y = sp[(size_t)1 << rr_shift];
            o.z = sp[(size_t)2 << rr_shift];
            o.w = sp[(size_t)3 << rr_shift];
        }
        ws4[t] = o;       // quad region is identity-indexed by slot
    } else {
        // level-3 channel-last texel
        int t2 = t - QE2;
        int p  = t2 >> 20;
        int yx = t2 & 0xFFFFF;
        const float* sp = tp3 + ((size_t)(p << 2) << 20) + yx;
        float4 o;
        o.x = sp[0];
        o.y = sp[(size_t)1 << 20];
        o.z = sp[(size_t)2 << 20];
        o.w = sp[(size_t)3 << 20];
        ws4[t] = o;
    }
}

// ---------------- bilinear helpers ----------------
struct BilinW {
    int i00, i10, i01, i11;
    float w00, w10, w01, w11;
};

__device__ __forceinline__ BilinW bilin_weights(int r, float u, float v) {
    float fr = (float)r;
    float fx = (u + 1.0f) * 0.5f * fr - 0.5f;
    float fy = (v + 1.0f) * 0.5f * fr - 0.5f;
    float x0f = floorf(fx), y0f = floorf(fy);
    float wx = fx - x0f, wy = fy - y0f;
    int x0 = (int)x0f, y0 = (int)y0f;
    int x1 = x0 + 1, y1 = y0 + 1;
    float vx0 = ((unsigned)x0 < (unsigned)r) ? 1.0f : 0.0f;
    float vx1 = ((unsigned)x1 < (unsigned)r) ? 1.0f : 0.0f;
    float vy0 = ((unsigned)y0 < (unsigned)r) ? 1.0f : 0.0f;
    float vy1 = ((unsigned)y1 < (unsigned)r) ? 1.0f : 0.0f;
    int x0c = min(max(x0, 0), r - 1), x1c = min(max(x1, 0), r - 1);
    int y0c = min(max(y0, 0), r - 1), y1c = min(max(y1, 0), r - 1);
    BilinW b;
    b.i00 = y0c * r + x0c; b.i10 = y0c * r + x1c;
    b.i01 = y1c * r + x0c; b.i11 = y1c * r + x1c;
    b.w00 = (1.0f - wx) * (1.0f - wy) * vx0 * vy0;
    b.w10 = wx * (1.0f - wy) * vx1 * vy0;
    b.w01 = (1.0f - wx) * wy * vx0 * vy1;
    b.w11 = wx * wy * vx1 * vy1;
    return b;
}

__device__ __forceinline__ float line_w(float t) {
    float fx = (t + 1.0f) * 0.5f - 0.5f;     // W = 1 axis
    float x0f = floorf(fx);
    float wx = fx - x0f;
    int x0 = (int)x0f;
    float w = 0.0f;
    if (x0 == 0) w += 1.0f - wx;
    if (x0 == -1) w += wx;
    return w;
}

// ==================== tier-1 main: thread = (point, level*3+plane) ====================
template <bool VEC4OUT>
__global__ __launch_bounds__(256) void tri12(const float* __restrict__ x,
                                             const f32x4* __restrict__ ws4,
                                             const float* __restrict__ S,
                                             float* __restrict__ out, int N) {
    int gid = blockIdx.x * 256 + threadIdx.x;
    int n = gid / 12;
    int k = gid - n * 12;        // k = l*3 + p, fastest -> out4[gid] dense
    if (n >= N) return;
    float ax = x[n * 3 + 0] * 2.0f - 1.0f;
    float ay = x[n * 3 + 1] * 2.0f - 1.0f;
    float az = x[n * 3 + 2] * 2.0f - 1.0f;
    int l = k / 3;
    int p = k - l * 3;
    // plane p (u = W axis, v = H axis): p0:(x,z) p1:(y,x) p2:(z,y)
    float u = (p == 0) ? ax : (p == 1) ? ay : az;
    float v = (p == 0) ? az : (p == 1) ? ax : ay;
    float lw = line_w(u);
    const f32x4* S4 = reinterpret_cast<const f32x4*>(S);
    f32x4 s = S4[k];

    f32x4 o;
    if (l < 3) {
        // pre-gathered 2x2 quad: one 64B-aligned chunk, pure bilinear weights
        int r = 128 << l, R = r + 1;
        float fr = (float)r;
        float fx = (u + 1.0f) * 0.5f * fr - 0.5f;
        float fy = (v + 1.0f) * 0.5f * fr - 0.5f;
        float x0f = floorf(fx), y0f = floorf(fy);
        float wx = fx - x0f, wy = fy - y0f;
        int ix = (int)x0f + 1;               // quad grid index = x0+1 in [0, r]
        int iy = (int)y0f + 1;
        ix = min(max(ix, 0), R - 1);         // defensive; in-range by construction
        iy = min(max(iy, 0), R - 1);
        int qbase = (l == 0) ? 0 : (l == 1) ? QE0 : QE1;
        const f32x4* Q = ws4 + qbase + (size_t)((p * R + iy) * R + ix) * 4;
        f32x4 q0 = Q[0], q1 = Q[1], q2 = Q[2], q3 = Q[3];
        float w00 = (1.0f - wx) * (1.0f - wy), w10 = wx * (1.0f - wy);
        float w01 = (1.0f - wx) * wy,          w11 = wx * wy;
        o = q0 * w00 + q1 * w10 + q2 * w01 + q3 * w11;
    } else {
        // level 3: channel-last texels, 4-corner gather with baked validity
        BilinW b = bilin_weights(1024, u, v);
        const f32x4* G = ws4 + QE2 + (size_t)p * 1048576;
        f32x4 g0 = G[b.i00], g1 = G[b.i10], g2 = G[b.i01], g3 = G[b.i11];
        o = g0 * b.w00 + g1 * b.w10 + g2 * b.w01 + g3 * b.w11;
    }
    o = o * (s * lw);

    if (VEC4OUT) {
        __builtin_nontemporal_store(o, reinterpret_cast<f32x4*>(out) + gid);
    } else {
        size_t base = (size_t)gid * 4;
        out[base + 0] = o.x; out[base + 1] = o.y;
        out[base + 2] = o.z; out[base + 3] = o.w;
    }
}

// ==================== tier-2 (R1 path, verified): repack + split4 ====================
__global__ __launch_bounds__(256) void repack_all(
        const float* __restrict__ tp0, const float* __restrict__ tp1,
        const float* __restrict__ tp2, const float* __restrict__ tp3,
        const float* __restrict__ tl0, const float* __restrict__ tl1,
        const float* __restrict__ tl2, const float* __restrict__ tl3,
        float* __restrict__ ws) {
    int t = blockIdx.x * 256 + threadIdx.x;
    const float* src; int rr_shift, texoff;
    if (t < 49152)        { src = tp0; rr_shift = 14; texoff = 0; }
    else if (t < 245760)  { src = tp1; rr_shift = 16; texoff = 49152; }
    else if (t < 1032192) { src = tp2; rr_shift = 18; texoff = 245760; }
    else                  { src = tp3; rr_shift = 20; texoff = 1032192; }
    int local = t - texoff;
    int p  = local >> rr_shift;
    int yx = local & ((1 << rr_shift) - 1);
    const float* s0 = src + ((size_t)(p << 2) << rr_shift) + yx;
    float4 o;
    o.x = s0[0];
    o.y = s0[(size_t)1 << rr_shift];
    o.z = s0[(size_t)2 << rr_shift];
    o.w = s0[(size_t)3 << rr_shift];
    reinterpret_cast<float4*>(ws)[t] = o;
    if (t < 48) {
        int ll = t / 12, rem = t % 12, pp = rem >> 2, cc = rem & 3;
        const float* tl = (ll == 0) ? tl0 : (ll == 1) ? tl1 : (ll == 2) ? tl2 : tl3;
        int r = 128 << ll;
        const float* row = tl + (size_t)((pp << 2) + cc) * r;
        int y0 = (r >> 1) - 1;
        ws[S_OFF2 + t] = 0.5f * row[y0] + 0.5f * row[y0 + 1];
    }
}

__device__ __forceinline__ f32x4 bacc(const float4& A, const float4& B2,
                                      const float4& C2, const float4& D,
                                      const BilinW& b, const float4& s, float lwv) {
    f32x4 o;
    o.x = (A.x * b.w00 + B2.x * b.w10 + C2.x * b.w01 + D.x * b.w11) * (s.x * lwv);
    o.y = (A.y * b.w00 + B2.y * b.w10 + C2.y * b.w01 + D.y * b.w11) * (s.y * lwv);
    o.z = (A.z * b.w00 + B2.z * b.w10 + C2.z * b.w01 + D.z * b.w11) * (s.z * lwv);
    o.w = (A.w * b.w00 + B2.w * b.w10 + C2.w * b.w01 + D.w * b.w11) * (s.w * lwv);
    return o;
}

template <bool VEC4OUT>
__global__ __launch_bounds__(256, 2) void tri_split4(
        const float* __restrict__ x, const float4* __restrict__ planes,
        const float* __restrict__ S, float* __restrict__ out, int N) {
    int gid = blockIdx.x * 256 + threadIdx.x;
    int n = gid >> 2;
    int l = gid & 3;
    if (n >= N) return;
    float ax = x[n * 3 + 0] * 2.0f - 1.0f;
    float ay = x[n * 3 + 1] * 2.0f - 1.0f;
    float az = x[n * 3 + 2] * 2.0f - 1.0f;
    const int r = 128 << l;
    const int rr = r * r;
    int texoff = (l == 0) ? 0 : (l == 1) ? 49152 : (l == 2) ? 245760 : 1032192;
    const float4* G0 = planes + texoff;
    const float4* G1 = G0 + rr;
    const float4* G2 = G1 + rr;
    BilinW b0 = bilin_weights(r, ax, az);
    BilinW b1 = bilin_weights(r, ay, ax);
    BilinW b2 = bilin_weights(r, az, ay);
    float4 g0a = G0[b0.i00], g0b = G0[b0.i10], g0c = G0[b0.i01], g0d = G0[b0.i11];
    float4 g1a = G1[b1.i00], g1b = G1[b1.i10], g1c = G1[b1.i01], g1d = G1[b1.i11];
    float4 g2a = G2[b2.i00], g2b = G2[b2.i10], g2c = G2[b2.i01], g2d = G2[b2.i11];
    float lw0 = line_w(ax), lw1 = line_w(ay), lw2 = line_w(az);
    const float4* S4 = reinterpret_cast<const float4*>(S);
    float4 s0 = S4[l * 3 + 0], s1 = S4[l * 3 + 1], s2 = S4[l * 3 + 2];

    f32x4 o0 = bacc(g0a, g0b, g0c, g0d, b0, s0, lw0);
    f32x4 o1 = bacc(g1a, g1b, g1c, g1d, b1, s1, lw1);
    f32x4 o2 = bacc(g2a, g2b, g2c, g2d, b2, s2, lw2);

    size_t base = (size_t)n * 48 + (size_t)l * 12;
    if (VEC4OUT) {
        f32x4* op = reinterpret_cast<f32x4*>(out + base);
        __builtin_nontemporal_store(o0, op);
        __builtin_nontemporal_store(o1, op + 1);
        __builtin_nontemporal_store(o2, op + 2);
    } else {
        out[base + 0] = o0.x; out[base + 1]  = o0.y;
        out[base + 2] = o0.z; out[base + 3]  = o0.w;
        out[base + 4] = o1.x; out[base + 5]  = o1.y;
        out[base + 6] = o1.z; out[base + 7]  = o1.w;
        out[base + 8] = o2.x; out[base + 9]  = o2.y;
        out[base + 10] = o2.z; out[base + 11] = o2.w;
    }
}

// ==================== tier-3 fallback: direct layout ====================
__global__ __launch_bounds__(256) void tri_direct(
        const float* __restrict__ x,
        const float* __restrict__ tp0, const float* __restrict__ tp1,
        const float* __restrict__ tp2, const float* __restrict__ tp3,
        const float* __restrict__ tl0, const float* __restrict__ tl1,
        const float* __restrict__ tl2, const float* __restrict__ tl3,
        float* __restrict__ out, int N) {
    int n = blockIdx.x * blockDim.x + threadIdx.x;
    if (n >= N) return;
    float ax = x[n * 3 + 0] * 2.0f - 1.0f;
    float ay = x[n * 3 + 1] * 2.0f - 1.0f;
    float az = x[n * 3 + 2] * 2.0f - 1.0f;
    const float U[3] = {ax, ay, az};
    const float V[3] = {az, ax, ay};
    const float LW[3] = {line_w(ax), line_w(ay), line_w(az)};
    const float* TP[4] = {tp0, tp1, tp2, tp3};
    const float* TL[4] = {tl0, tl1, tl2, tl3};

#pragma unroll
    for (int l = 0; l < 4; ++l) {
        const int r = 128 << l;
        const int rr = r * r;
        const int y0 = (r >> 1) - 1;
#pragma unroll
        for (int p = 0; p < 3; ++p) {
            const float* G = TP[l] + (size_t)(p * 4) * rr;
            BilinW b = bilin_weights(r, U[p], V[p]);
            const float w = LW[p];
#pragma unroll
            for (int c = 0; c < 4; ++c) {
                const float* Gc = G + (size_t)c * rr;
                float acc = Gc[b.i00] * b.w00 + Gc[b.i10] * b.w10 +
                            Gc[b.i01] * b.w01 + Gc[b.i11] * b.w11;
                const float* row = TL[l] + (size_t)((p << 2) + c) * r;
                float s = 0.5f * row[y0] + 0.5f * row[y0 + 1];
                out[(size_t)n * 48 + l * 12 + p * 4 + c] = acc * (s * w);
            }
        }
    }
}

extern "C" void kernel_launch(void* const* d_in, const int* in_sizes, int n_in,
                              void* d_out, int out_size, void* d_ws, size_t ws_size,
                              hipStream_t stream) {
    const float* x = (const float*)d_in[0];
    const float* tp[4];
    const float* tl[4];
    // setup_inputs() dict order is interleaved: x, tp0, tl0, tp1, tl1, ...
    bool interleaved = (n_in >= 9) && (in_sizes[2] == 1536);
    for (int l = 0; l < 4; ++l) {
        if (interleaved) {
            tp[l] = (const float*)d_in[1 + 2 * l];
            tl[l] = (const float*)d_in[2 + 2 * l];
        } else {
            tp[l] = (const float*)d_in[1 + l];
            tl[l] = (const float*)d_in[5 + l];
        }
    }
    int N = in_sizes[0] / 3;
    float* out = (float*)d_out;
    bool out16 = (((uintptr_t)d_out & 15u) == 0);

    if (ws_size >= WS1_NEED && (((uintptr_t)d_ws & 63u) == 0)) {
        // tier 1: 2x2-quad path
        float* ws = (float*)d_ws;
        int prep_grid = (TOTAL_SLOTS + 255) / 256;
        prep_all<<<prep_grid, 256, 0, stream>>>(
            tp[0], tp[1], tp[2], tp[3], tl[0], tl[1], tl[2], tl[3], ws);
        long long total = 12LL * N;
        int grid = (int)((total + 255) / 256);
        if (out16) {
            tri12<true><<<grid, 256, 0, stream>>>(
                x, (const f32x4*)ws, ws + S_OFFF, out, N);
        } else {
            tri12<false><<<grid, 256, 0, stream>>>(
                x, (const f32x4*)ws, ws + S_OFFF, out, N);
        }
    } else if (ws_size >= WS2_NEED && (((uintptr_t)d_ws & 15u) == 0)) {
        // tier 2: R1 verified path
        float* ws = (float*)d_ws;
        repack_all<<<TEXELS / 256, 256, 0, stream>>>(
            tp[0], tp[1], tp[2], tp[3], tl[0], tl[1], tl[2], tl[3], ws);
        long long total = 4LL * N;
        int grid = (int)((total + 255) / 256);
        if (out16) {
            tri_split4<true><<<grid, 256, 0, stream>>>(
                x, (const float4*)ws, ws + S_OFF2, out, N);
        } else {
            tri_split4<false><<<grid, 256, 0, stream>>>(
                x, (const float4*)ws, ws + S_OFF2, out, N);
        }
    } else {
        int grid = (N + 255) / 256;
        tri_direct<<<grid, 256, 0, stream>>>(
            x, tp[0], tp[1], tp[2], tp[3], tl[0], tl[1], tl[2], tl[3], out, N);
    }
}

// Round 3
// 536.335 us; speedup vs baseline: 1.2314x; 1.0410x over previous
//
#include <hip/hip_runtime.h>
#include <cstdint>

// TriplaneEncoding, fp32 I/O. N=2^20 points, 4 levels (r=128,256,512,1024),
// C=4, 3 planes.  out[n, l*12 + p*4 + c] = plane_bilinear * line
// Line sample is degenerate: line = w(t) * 0.5*(TL[p,c,r/2-1] + TL[p,c,r/2]).
//
// R7 design: R0-R2 all pinned at ~3.9 TB/s of L2-miss fabric traffic -> time
// is bytes/3.9TB/s. R2 fetch breakdown: level-3 scattered 4-corner gathers are
// ~480 MB of the 968 MB. Fix: pre-gathered 2x2 quads for ALL levels (one 64B
// line per sample). Tables = 268 MB (slightly past IF 256 MB; ~5% spill goes
// to HBM which has headroom). Tiers: all-quad (268MB) > R2 path (117MB) >
// direct, so no regression if ws is too small.

typedef float f32x4 __attribute__((ext_vector_type(4)));

// ---------------- tier-1 workspace layout (float4-slot units) ----------------
// [ quads L0 | quads L1 | quads L2 | quads L3 | S(48 floats) ]
// level quad table: 3 planes x (r+1)^2 quads x 4 slots (64B/quad), OOB = 0.
static constexpr int Q1_0 = 0;
static constexpr int Q1_1 = 199692;             // + 4*3*129^2
static constexpr int Q1_2 = 992280;             // + 4*3*257^2
static constexpr int Q1_3 = 4150308;            // + 4*3*513^2
static constexpr int Q1_END = 16757808;         // + 4*3*1025^2
static constexpr int S1_OFF = Q1_END * 4;       // float offset = 67031232
static constexpr size_t WS1_NEED = ((size_t)S1_OFF + 48) * sizeof(float); // ~268.1 MB

// ---------------- tier-2 (R2 verified) workspace layout ----------------
static constexpr int QE0 = 199692;
static constexpr int QE1 = 992280;
static constexpr int QE2 = 4150308;
static constexpr int L3T = 3145728;             // 3*1024^2 texels
static constexpr int T2_TOTAL = QE2 + L3T;
static constexpr int S2_OFF = (QE2 + L3T) * 4;
static constexpr size_t WS2_NEED = (size_t)(S2_OFF + 48) * sizeof(float); // ~116.7 MB

// ==================== tier-1 prep: quads all levels + S ====================
__global__ __launch_bounds__(256) void prep_quads_all(
        const float* __restrict__ tp0, const float* __restrict__ tp1,
        const float* __restrict__ tp2, const float* __restrict__ tp3,
        const float* __restrict__ tl0, const float* __restrict__ tl1,
        const float* __restrict__ tl2, const float* __restrict__ tl3,
        float* __restrict__ ws) {
    int t = blockIdx.x * 256 + threadIdx.x;
    if (t < 48) {   // line constants: rows r/2-1, r/2 at weight 0.5 each
        int ll = t / 12, rem = t % 12, pp = rem >> 2, cc = rem & 3;
        const float* tl = (ll == 0) ? tl0 : (ll == 1) ? tl1 : (ll == 2) ? tl2 : tl3;
        int r = 128 << ll;
        const float* row = tl + (size_t)((pp << 2) + cc) * r;
        int y0 = (r >> 1) - 1;
        ws[S1_OFF + t] = 0.5f * row[y0] + 0.5f * row[y0 + 1];
    }
    if (t >= Q1_END) return;
    const float* src; int lvl, base;
    if (t < Q1_1)      { src = tp0; lvl = 0; base = Q1_0; }
    else if (t < Q1_2) { src = tp1; lvl = 1; base = Q1_1; }
    else if (t < Q1_3) { src = tp2; lvl = 2; base = Q1_2; }
    else               { src = tp3; lvl = 3; base = Q1_3; }
    int lt = t - base;
    int q = lt >> 2, s = lt & 3;                // quad id, corner slot
    int r = 128 << lvl, R = r + 1, rr_shift = 2 * (7 + lvl);
    int RR = R * R;
    int p   = q / RR;
    int rem = q - p * RR;
    int yq  = rem / R;
    int xq  = rem - yq * R;
    int tx = xq - 1 + (s & 1);
    int ty = yq - 1 + (s >> 1);
    float4 o = {0.f, 0.f, 0.f, 0.f};
    if ((unsigned)tx < (unsigned)r && (unsigned)ty < (unsigned)r) {
        const float* sp = src + ((size_t)(p << 2) << rr_shift) + (size_t)ty * r + tx;
        o.x = sp[0];
        o.y = sp[(size_t)1 << rr_shift];
        o.z = sp[(size_t)2 << rr_shift];
        o.w = sp[(size_t)3 << rr_shift];
    }
    reinterpret_cast<float4*>(ws)[t] = o;       // identity-indexed by slot
}

// ---------------- helpers ----------------
struct BilinW {
    int i00, i10, i01, i11;
    float w00, w10, w01, w11;
};

__device__ __forceinline__ BilinW bilin_weights(int r, float u, float v) {
    float fr = (float)r;
    float fx = (u + 1.0f) * 0.5f * fr - 0.5f;
    float fy = (v + 1.0f) * 0.5f * fr - 0.5f;
    float x0f = floorf(fx), y0f = floorf(fy);
    float wx = fx - x0f, wy = fy - y0f;
    int x0 = (int)x0f, y0 = (int)y0f;
    int x1 = x0 + 1, y1 = y0 + 1;
    float vx0 = ((unsigned)x0 < (unsigned)r) ? 1.0f : 0.0f;
    float vx1 = ((unsigned)x1 < (unsigned)r) ? 1.0f : 0.0f;
    float vy0 = ((unsigned)y0 < (unsigned)r) ? 1.0f : 0.0f;
    float vy1 = ((unsigned)y1 < (unsigned)r) ? 1.0f : 0.0f;
    int x0c = min(max(x0, 0), r - 1), x1c = min(max(x1, 0), r - 1);
    int y0c = min(max(y0, 0), r - 1), y1c = min(max(y1, 0), r - 1);
    BilinW b;
    b.i00 = y0c * r + x0c; b.i10 = y0c * r + x1c;
    b.i01 = y1c * r + x0c; b.i11 = y1c * r + x1c;
    b.w00 = (1.0f - wx) * (1.0f - wy) * vx0 * vy0;
    b.w10 = wx * (1.0f - wy) * vx1 * vy0;
    b.w01 = (1.0f - wx) * wy * vx0 * vy1;
    b.w11 = wx * wy * vx1 * vy1;
    return b;
}

__device__ __forceinline__ float line_w(float t) {
    float fx = (t + 1.0f) * 0.5f - 0.5f;     // W = 1 axis
    float x0f = floorf(fx);
    float wx = fx - x0f;
    int x0 = (int)x0f;
    float w = 0.0f;
    if (x0 == 0) w += 1.0f - wx;
    if (x0 == -1) w += wx;
    return w;
}

// ==================== tier-1 main: thread = (point, level*3+plane) ====================
template <bool VEC4OUT>
__global__ __launch_bounds__(256) void tri12q(const float* __restrict__ x,
                                              const f32x4* __restrict__ ws4,
                                              const float* __restrict__ S,
                                              float* __restrict__ out, int N) {
    int gid = blockIdx.x * 256 + threadIdx.x;
    int n = gid / 12;
    int k = gid - n * 12;        // k = l*3 + p, fastest -> out4[gid] dense
    if (n >= N) return;
    float ax = x[n * 3 + 0] * 2.0f - 1.0f;
    float ay = x[n * 3 + 1] * 2.0f - 1.0f;
    float az = x[n * 3 + 2] * 2.0f - 1.0f;
    int l = k / 3;
    int p = k - l * 3;
    // plane p (u = W axis, v = H axis): p0:(x,z) p1:(y,x) p2:(z,y)
    float u = (p == 0) ? ax : (p == 1) ? ay : az;
    float v = (p == 0) ? az : (p == 1) ? ax : ay;
    float lw = line_w(u);
    f32x4 s = reinterpret_cast<const f32x4*>(S)[k];

    // pre-gathered 2x2 quad: one 64B-aligned chunk, pure bilinear weights
    int r = 128 << l, R = r + 1;
    float fr = (float)r;
    float fx = (u + 1.0f) * 0.5f * fr - 0.5f;
    float fy = (v + 1.0f) * 0.5f * fr - 0.5f;
    float x0f = floorf(fx), y0f = floorf(fy);
    float wx = fx - x0f, wy = fy - y0f;
    int ix = (int)x0f + 1;               // quad grid index in [0, r]
    int iy = (int)y0f + 1;
    ix = min(max(ix, 0), R - 1);         // defensive; in-range by construction
    iy = min(max(iy, 0), R - 1);
    int qbase = (l == 0) ? Q1_0 : (l == 1) ? Q1_1 : (l == 2) ? Q1_2 : Q1_3;
    const f32x4* Q = ws4 + qbase + (size_t)((p * R + iy) * R + ix) * 4;
    f32x4 q0 = Q[0], q1 = Q[1], q2 = Q[2], q3 = Q[3];
    float w00 = (1.0f - wx) * (1.0f - wy), w10 = wx * (1.0f - wy);
    float w01 = (1.0f - wx) * wy,          w11 = wx * wy;
    f32x4 o = q0 * w00 + q1 * w10 + q2 * w01 + q3 * w11;
    o = o * (s * lw);

    if (VEC4OUT) {
        __builtin_nontemporal_store(o, reinterpret_cast<f32x4*>(out) + gid);
    } else {
        size_t base = (size_t)gid * 4;
        out[base + 0] = o.x; out[base + 1] = o.y;
        out[base + 2] = o.z; out[base + 3] = o.w;
    }
}

// ==================== tier-2 (R2 verified): quads L0-2 + L3 texels ====================
__global__ __launch_bounds__(256) void prep_all(
        const float* __restrict__ tp0, const float* __restrict__ tp1,
        const float* __restrict__ tp2, const float* __restrict__ tp3,
        const float* __restrict__ tl0, const float* __restrict__ tl1,
        const float* __restrict__ tl2, const float* __restrict__ tl3,
        float* __restrict__ ws) {
    int t = blockIdx.x * 256 + threadIdx.x;
    if (t < 48) {
        int ll = t / 12, rem = t % 12, pp = rem >> 2, cc = rem & 3;
        const float* tl = (ll == 0) ? tl0 : (ll == 1) ? tl1 : (ll == 2) ? tl2 : tl3;
        int r = 128 << ll;
        const float* row = tl + (size_t)((pp << 2) + cc) * r;
        int y0 = (r >> 1) - 1;
        ws[S2_OFF + t] = 0.5f * row[y0] + 0.5f * row[y0 + 1];
    }
    if (t >= T2_TOTAL) return;
    float4* ws4 = reinterpret_cast<float4*>(ws);
    if (t < QE2) {
        const float* src; int lvl, base;
        if (t < QE0)      { src = tp0; lvl = 0; base = 0; }
        else if (t < QE1) { src = tp1; lvl = 1; base = QE0; }
        else              { src = tp2; lvl = 2; base = QE1; }
        int lt = t - base;
        int q = lt >> 2, s = lt & 3;
        int r = 128 << lvl, R = r + 1, rr_shift = 2 * (7 + lvl);
        int RR = R * R;
        int p   = q / RR;
        int rem = q - p * RR;
        int yq  = rem / R;
        int xq  = rem - yq * R;
        int tx = xq - 1 + (s & 1);
        int ty = yq - 1 + (s >> 1);
        float4 o = {0.f, 0.f, 0.f, 0.f};
        if ((unsigned)tx < (unsigned)r && (unsigned)ty < (unsigned)r) {
            const float* sp = src + ((size_t)(p << 2) << rr_shift) + (size_t)ty * r + tx;
            o.x = sp[0];
            o.y = sp[(size_t)1 << rr_shift];
            o.z = sp[(size_t)2 << rr_shift];
            o.w = sp[(size_t)3 << rr_shift];
        }
        ws4[t] = o;
    } else {
        int t2 = t - QE2;
        int p  = t2 >> 20;
        int yx = t2 & 0xFFFFF;
        const float* sp = tp3 + ((size_t)(p << 2) << 20) + yx;
        float4 o;
        o.x = sp[0];
        o.y = sp[(size_t)1 << 20];
        o.z = sp[(size_t)2 << 20];
        o.w = sp[(size_t)3 << 20];
        ws4[t] = o;
    }
}

template <bool VEC4OUT>
__global__ __launch_bounds__(256) void tri12(const float* __restrict__ x,
                                             const f32x4* __restrict__ ws4,
                                             const float* __restrict__ S,
                                             float* __restrict__ out, int N) {
    int gid = blockIdx.x * 256 + threadIdx.x;
    int n = gid / 12;
    int k = gid - n * 12;
    if (n >= N) return;
    float ax = x[n * 3 + 0] * 2.0f - 1.0f;
    float ay = x[n * 3 + 1] * 2.0f - 1.0f;
    float az = x[n * 3 + 2] * 2.0f - 1.0f;
    int l = k / 3;
    int p = k - l * 3;
    float u = (p == 0) ? ax : (p == 1) ? ay : az;
    float v = (p == 0) ? az : (p == 1) ? ax : ay;
    float lw = line_w(u);
    f32x4 s = reinterpret_cast<const f32x4*>(S)[k];

    f32x4 o;
    if (l < 3) {
        int r = 128 << l, R = r + 1;
        float fr = (float)r;
        float fx = (u + 1.0f) * 0.5f * fr - 0.5f;
        float fy = (v + 1.0f) * 0.5f * fr - 0.5f;
        float x0f = floorf(fx), y0f = floorf(fy);
        float wx = fx - x0f, wy = fy - y0f;
        int ix = (int)x0f + 1;
        int iy = (int)y0f + 1;
        ix = min(max(ix, 0), R - 1);
        iy = min(max(iy, 0), R - 1);
        int qbase = (l == 0) ? 0 : (l == 1) ? QE0 : QE1;
        const f32x4* Q = ws4 + qbase + (size_t)((p * R + iy) * R + ix) * 4;
        f32x4 q0 = Q[0], q1 = Q[1], q2 = Q[2], q3 = Q[3];
        float w00 = (1.0f - wx) * (1.0f - wy), w10 = wx * (1.0f - wy);
        float w01 = (1.0f - wx) * wy,          w11 = wx * wy;
        o = q0 * w00 + q1 * w10 + q2 * w01 + q3 * w11;
    } else {
        BilinW b = bilin_weights(1024, u, v);
        const f32x4* G = ws4 + QE2 + (size_t)p * 1048576;
        f32x4 g0 = G[b.i00], g1 = G[b.i10], g2 = G[b.i01], g3 = G[b.i11];
        o = g0 * b.w00 + g1 * b.w10 + g2 * b.w01 + g3 * b.w11;
    }
    o = o * (s * lw);

    if (VEC4OUT) {
        __builtin_nontemporal_store(o, reinterpret_cast<f32x4*>(out) + gid);
    } else {
        size_t base = (size_t)gid * 4;
        out[base + 0] = o.x; out[base + 1] = o.y;
        out[base + 2] = o.z; out[base + 3] = o.w;
    }
}

// ==================== tier-3 fallback: direct layout ====================
__global__ __launch_bounds__(256) void tri_direct(
        const float* __restrict__ x,
        const float* __restrict__ tp0, const float* __restrict__ tp1,
        const float* __restrict__ tp2, const float* __restrict__ tp3,
        const float* __restrict__ tl0, const float* __restrict__ tl1,
        const float* __restrict__ tl2, const float* __restrict__ tl3,
        float* __restrict__ out, int N) {
    int n = blockIdx.x * blockDim.x + threadIdx.x;
    if (n >= N) return;
    float ax = x[n * 3 + 0] * 2.0f - 1.0f;
    float ay = x[n * 3 + 1] * 2.0f - 1.0f;
    float az = x[n * 3 + 2] * 2.0f - 1.0f;
    const float U[3] = {ax, ay, az};
    const float V[3] = {az, ax, ay};
    const float LW[3] = {line_w(ax), line_w(ay), line_w(az)};
    const float* TP[4] = {tp0, tp1, tp2, tp3};
    const float* TL[4] = {tl0, tl1, tl2, tl3};

#pragma unroll
    for (int l = 0; l < 4; ++l) {
        const int r = 128 << l;
        const int rr = r * r;
        const int y0 = (r >> 1) - 1;
#pragma unroll
        for (int p = 0; p < 3; ++p) {
            const float* G = TP[l] + (size_t)(p * 4) * rr;
            BilinW b = bilin_weights(r, U[p], V[p]);
            const float w = LW[p];
#pragma unroll
            for (int c = 0; c < 4; ++c) {
                const float* Gc = G + (size_t)c * rr;
                float acc = Gc[b.i00] * b.w00 + Gc[b.i10] * b.w10 +
                            Gc[b.i01] * b.w01 + Gc[b.i11] * b.w11;
                const float* row = TL[l] + (size_t)((p << 2) + c) * r;
                float s = 0.5f * row[y0] + 0.5f * row[y0 + 1];
                out[(size_t)n * 48 + l * 12 + p * 4 + c] = acc * (s * w);
            }
        }
    }
}

extern "C" void kernel_launch(void* const* d_in, const int* in_sizes, int n_in,
                              void* d_out, int out_size, void* d_ws, size_t ws_size,
                              hipStream_t stream) {
    const float* x = (const float*)d_in[0];
    const float* tp[4];
    const float* tl[4];
    // setup_inputs() dict order is interleaved: x, tp0, tl0, tp1, tl1, ...
    bool interleaved = (n_in >= 9) && (in_sizes[2] == 1536);
    for (int l = 0; l < 4; ++l) {
        if (interleaved) {
            tp[l] = (const float*)d_in[1 + 2 * l];
            tl[l] = (const float*)d_in[2 + 2 * l];
        } else {
            tp[l] = (const float*)d_in[1 + l];
            tl[l] = (const float*)d_in[5 + l];
        }
    }
    int N = in_sizes[0] / 3;
    float* out = (float*)d_out;
    bool out16 = (((uintptr_t)d_out & 15u) == 0);

    if (ws_size >= WS1_NEED && (((uintptr_t)d_ws & 63u) == 0)) {
        // tier 1: all-level quad path
        float* ws = (float*)d_ws;
        int prep_grid = (Q1_END + 255) / 256;
        prep_quads_all<<<prep_grid, 256, 0, stream>>>(
            tp[0], tp[1], tp[2], tp[3], tl[0], tl[1], tl[2], tl[3], ws);
        long long total = 12LL * N;
        int grid = (int)((total + 255) / 256);
        if (out16) {
            tri12q<true><<<grid, 256, 0, stream>>>(
                x, (const f32x4*)ws, ws + S1_OFF, out, N);
        } else {
            tri12q<false><<<grid, 256, 0, stream>>>(
                x, (const f32x4*)ws, ws + S1_OFF, out, N);
        }
    } else if (ws_size >= WS2_NEED && (((uintptr_t)d_ws & 63u) == 0)) {
        // tier 2: R2 verified path (quads L0-2, texels L3)
        float* ws = (float*)d_ws;
        int prep_grid = (T2_TOTAL + 255) / 256;
        prep_all<<<prep_grid, 256, 0, stream>>>(
            tp[0], tp[1], tp[2], tp[3], tl[0], tl[1], tl[2], tl[3], ws);
        long long total = 12LL * N;
        int grid = (int)((total + 255) / 256);
        if (out16) {
            tri12<true><<<grid, 256, 0, stream>>>(
                x, (const f32x4*)ws, ws + S2_OFF, out, N);
        } else {
            tri12<false><<<grid, 256, 0, stream>>>(
                x, (const f32x4*)ws, ws + S2_OFF, out, N);
        }
    } else {
        int grid = (N + 255) / 256;
        tri_direct<<<grid, 256, 0, stream>>>(
            x, tp[0], tp[1], tp[2], tp[3], tl[0], tl[1], tl[2], tl[3], out, N);
    }
}